// Round 3
// baseline (1213.989 us; speedup 1.0000x reference)
//
#include <hip/hip_runtime.h>

#define SEQ  2048
#define HID  128
#define NB   32
#define TILE 64            // owned output rows per block
#define ROWS 72            // staged rows: s0-3 .. s0+68 (incl. 3-halo + 2 pad)
#define HSTR 132           // hbuf row stride (16B-aligned, conflict-safe)

// ---------------------------------------------------------------------------
// Fully fused enc1 -> enc2 -> gc1 -> gc2 -> gc3 -> pool.
// One block per (64-row seq tile, batch); 256 threads; per-thread tile
// 9 rows x 4 cols (ty = tid>>5 owns rows ty*9..ty*9+8, tx4 = (tid&31)*4).
// Activations live in hbuf (LDS). W k-slices are double-buffered in LDS with
// register prefetch -> one barrier per k-slice. Tridiagonal aggregation is
// done in registers; only strip-boundary rows exchange through LDS.
// Validity telescoping: rows with correct values shrink 1/side per gc layer:
// enc [0,71] -> gc1 [1,70] -> gc2 [2,69] -> gc3 [3,68] ⊇ owned [3,66].
// LDS = 38016 + 32768 + 512 + 4096 = 75392 B -> 2 blocks/CU.
// ---------------------------------------------------------------------------
__global__ __launch_bounds__(256, 2) void fused_kernel(
    const float* __restrict__ x,
    const float* __restrict__ enc_w1, const float* __restrict__ enc_b1,
    const float* __restrict__ enc_w2, const float* __restrict__ enc_b2,
    const float* __restrict__ gc1_w, const float* __restrict__ gc1_b,
    const float* __restrict__ gc2_w, const float* __restrict__ gc2_b,
    const float* __restrict__ gc3_w, const float* __restrict__ gc3_b,
    float* __restrict__ pooled)
{
  __shared__ __align__(16) float hbuf[ROWS * HSTR];   // 38016 B activations
  __shared__ __align__(16) float wbuf[2][32 * HID];   // 32768 B W double-buffer
  __shared__ float bsh[HID];                          // current layer bias
  __shared__ float psum[8][HID];                      // pool partials

  const int tid = threadIdx.x;
  const int tx4 = (tid & 31) * 4;
  const int ty  = tid >> 5;          // 0..7
  const int r0  = ty * 9;
  const int s0  = blockIdx.x * TILE;
  const int b   = blockIdx.y;

  // ---------------- enc1: h1 = relu(x @ w1 + b1) -> hbuf ----------------
  {
    float* xs  = wbuf[1];            // [ROWS][6]
    float* w1s = wbuf[1] + 512;      // [6][128]
    for (int f = tid; f < ROWS * 6; f += 256) {
      const int m = f / 6, c = f - m * 6;
      const int s = s0 - 3 + m;
      xs[f] = (s >= 0 && s < SEQ) ? x[((long long)b * SEQ + s) * 6 + c] : 0.f;
    }
    for (int f = tid; f < 6 * HID; f += 256) w1s[f] = enc_w1[f];
    if (tid < HID) bsh[tid] = enc_b1[tid];
    __syncthreads();

    float acc[9][4];
    #pragma unroll
    for (int i = 0; i < 9; ++i)
      acc[i][0] = acc[i][1] = acc[i][2] = acc[i][3] = 0.f;
    #pragma unroll
    for (int k = 0; k < 6; ++k) {
      const float4 w = *(const float4*)&w1s[k * HID + tx4];
      #pragma unroll
      for (int i = 0; i < 9; ++i) {
        const float a = xs[(r0 + i) * 6 + k];
        acc[i][0] = fmaf(a, w.x, acc[i][0]);
        acc[i][1] = fmaf(a, w.y, acc[i][1]);
        acc[i][2] = fmaf(a, w.z, acc[i][2]);
        acc[i][3] = fmaf(a, w.w, acc[i][3]);
      }
    }
    const float4 bb = *(const float4*)&bsh[tx4];
    #pragma unroll
    for (int i = 0; i < 9; ++i) {
      float4 o;
      o.x = fmaxf(acc[i][0] + bb.x, 0.f);
      o.y = fmaxf(acc[i][1] + bb.y, 0.f);
      o.z = fmaxf(acc[i][2] + bb.z, 0.f);
      o.w = fmaxf(acc[i][3] + bb.w, 0.f);
      *(float4*)&hbuf[(r0 + i) * HSTR + tx4] = o;
    }
    // publish handled by barrier (a)/(b) below
  }

  // ---------------- 4 x (128-K GEMM [+ tridiag agg + relu]) ----------------
  for (int L = 0; L < 4; ++L) {
    const float* __restrict__ Wg = (L == 0) ? enc_w2 : (L == 1) ? gc1_w
                                 : (L == 2) ? gc2_w  : gc3_w;
    const float* __restrict__ bg = (L == 0) ? enc_b2 : (L == 1) ? gc1_b
                                 : (L == 2) ? gc2_b  : gc3_b;
    const float4* Wg4 = (const float4*)Wg;

    float4 pre[4];
    #pragma unroll
    for (int q = 0; q < 4; ++q) pre[q] = Wg4[q * 256 + tid];   // slice 0
    __syncthreads();   // (a) prior wbuf/hbuf readers done; hbuf writes publish
    #pragma unroll
    for (int q = 0; q < 4; ++q) ((float4*)wbuf[0])[q * 256 + tid] = pre[q];
    if (tid < HID) bsh[tid] = bg[tid];
    #pragma unroll
    for (int q = 0; q < 4; ++q) pre[q] = Wg4[1024 + q * 256 + tid];  // slice 1
    __syncthreads();   // (b) publish wbuf[0] + bsh

    float acc[9][4];
    #pragma unroll
    for (int i = 0; i < 9; ++i)
      acc[i][0] = acc[i][1] = acc[i][2] = acc[i][3] = 0.f;

    for (int kb = 0; kb < 4; ++kb) {
      const float* wb = wbuf[kb & 1];
      const int kbase = kb * 32;
      #pragma unroll
      for (int k4 = 0; k4 < 8; ++k4) {
        const float4 w0 = *(const float4*)&wb[(k4 * 4 + 0) * HID + tx4];
        const float4 w1 = *(const float4*)&wb[(k4 * 4 + 1) * HID + tx4];
        const float4 w2 = *(const float4*)&wb[(k4 * 4 + 2) * HID + tx4];
        const float4 w3 = *(const float4*)&wb[(k4 * 4 + 3) * HID + tx4];
        #pragma unroll
        for (int i = 0; i < 9; ++i) {
          const float4 a = *(const float4*)&hbuf[(r0 + i) * HSTR + kbase + k4 * 4];
          acc[i][0] = fmaf(a.x, w0.x, acc[i][0]);
          acc[i][1] = fmaf(a.x, w0.y, acc[i][1]);
          acc[i][2] = fmaf(a.x, w0.z, acc[i][2]);
          acc[i][3] = fmaf(a.x, w0.w, acc[i][3]);
          acc[i][0] = fmaf(a.y, w1.x, acc[i][0]);
          acc[i][1] = fmaf(a.y, w1.y, acc[i][1]);
          acc[i][2] = fmaf(a.y, w1.z, acc[i][2]);
          acc[i][3] = fmaf(a.y, w1.w, acc[i][3]);
          acc[i][0] = fmaf(a.z, w2.x, acc[i][0]);
          acc[i][1] = fmaf(a.z, w2.y, acc[i][1]);
          acc[i][2] = fmaf(a.z, w2.z, acc[i][2]);
          acc[i][3] = fmaf(a.z, w2.w, acc[i][3]);
          acc[i][0] = fmaf(a.w, w3.x, acc[i][0]);
          acc[i][1] = fmaf(a.w, w3.y, acc[i][1]);
          acc[i][2] = fmaf(a.w, w3.z, acc[i][2]);
          acc[i][3] = fmaf(a.w, w3.w, acc[i][3]);
        }
      }
      if (kb < 3) {
        // write slice kb+1 (prefetched last iter); prefetch slice kb+2
        #pragma unroll
        for (int q = 0; q < 4; ++q)
          ((float4*)wbuf[(kb + 1) & 1])[q * 256 + tid] = pre[q];
        if (kb < 2) {
          #pragma unroll
          for (int q = 0; q < 4; ++q)
            pre[q] = Wg4[(kb + 2) * 1024 + q * 256 + tid];
        }
        __syncthreads();  // publish wbuf[(kb+1)&1]; old readers finished prior
      }
    }

    if (L == 0) {
      __syncthreads();   // (c0) all hbuf A-reads done
      const float4 bb = *(const float4*)&bsh[tx4];
      #pragma unroll
      for (int i = 0; i < 9; ++i) {
        float4 o;
        o.x = acc[i][0] + bb.x;  o.y = acc[i][1] + bb.y;
        o.z = acc[i][2] + bb.z;  o.w = acc[i][3] + bb.w;
        *(float4*)&hbuf[(r0 + i) * HSTR + tx4] = o;   // no relu after enc2
      }
    } else {
      // t = (in-sequence) ? acc + b : 0   (zero-padding of the reference)
      const float4 bb = *(const float4*)&bsh[tx4];
      float4 t4[9];
      #pragma unroll
      for (int i = 0; i < 9; ++i) {
        const int s = s0 - 3 + r0 + i;
        const bool v = (s >= 0 && s < SEQ);
        t4[i].x = v ? acc[i][0] + bb.x : 0.f;
        t4[i].y = v ? acc[i][1] + bb.y : 0.f;
        t4[i].z = v ? acc[i][2] + bb.z : 0.f;
        t4[i].w = v ? acc[i][3] + bb.w : 0.f;
      }
      // strip-boundary exchange through wbuf[0] (free: last read at kb=2)
      float* xb = wbuf[0];
      *(float4*)&xb[(ty * 2 + 0) * HID + tx4] = t4[0];
      *(float4*)&xb[(ty * 2 + 1) * HID + tx4] = t4[8];
      __syncthreads();   // (c) publish exchange; all hbuf A-reads done
      float4 tl = make_float4(0.f, 0.f, 0.f, 0.f), tr = tl;
      if (ty > 0) tl = *(const float4*)&xb[((ty - 1) * 2 + 1) * HID + tx4];
      if (ty < 7) tr = *(const float4*)&xb[((ty + 1) * 2 + 0) * HID + tx4];

      float4 pacc = make_float4(0.f, 0.f, 0.f, 0.f);
      #pragma unroll
      for (int i = 0; i < 9; ++i) {
        const int r = r0 + i;
        const int s = s0 - 3 + r;
        const float4 lf = (i == 0) ? tl : t4[i - 1];
        const float4 rt = (i == 8) ? tr : t4[i + 1];
        const float invd = (s == 0 || s == SEQ - 1) ? (1.0f / (2.0f + 1e-8f))
                                                    : (1.0f / (3.0f + 1e-8f));
        float4 h;
        h.x = fmaxf((lf.x + t4[i].x + rt.x) * invd, 0.f);
        h.y = fmaxf((lf.y + t4[i].y + rt.y) * invd, 0.f);
        h.z = fmaxf((lf.z + t4[i].z + rt.z) * invd, 0.f);
        h.w = fmaxf((lf.w + t4[i].w + rt.w) * invd, 0.f);
        if (L < 3) {
          *(float4*)&hbuf[r * HSTR + tx4] = h;        // published by next (a)
        } else if (r >= 3 && r <= 66) {               // pool owned rows only
          pacc.x += h.x; pacc.y += h.y; pacc.z += h.z; pacc.w += h.w;
        }
      }
      if (L == 3) {
        *(float4*)&psum[ty][tx4] = pacc;
        __syncthreads();
        if (tid < HID) {
          float v = 0.f;
          #pragma unroll
          for (int g = 0; g < 8; ++g) v += psum[g][tid];
          atomicAdd(&pooled[b * HID + tid], v);
        }
      }
    }
  }
}

// ---------------------------------------------------------------------------
// Classifier: out = relu(mean @ w1 + b1) @ w2 + b2, one block per batch row
// ---------------------------------------------------------------------------
__global__ __launch_bounds__(64) void cls_kernel(
    const float* __restrict__ pooled,
    const float* __restrict__ w1, const float* __restrict__ b1,
    const float* __restrict__ w2, const float* __restrict__ b2,
    float* __restrict__ out)
{
  __shared__ float ms[128];
  __shared__ float hid[64];
  const int b = blockIdx.x, tid = threadIdx.x;
  ms[tid] = pooled[b * 128 + tid] * (1.0f / 2048.0f);
  ms[tid + 64] = pooled[b * 128 + 64 + tid] * (1.0f / 2048.0f);
  __syncthreads();
  float a = b1[tid];
  for (int k = 0; k < 128; ++k) a = fmaf(ms[k], w1[k * 64 + tid], a);
  hid[tid] = a > 0.f ? a : 0.f;
  __syncthreads();
  if (tid < 3) {
    float o = b2[tid];
    for (int k = 0; k < 64; ++k) o = fmaf(hid[k], w2[k * 3 + tid], o);
    out[b * 3 + tid] = o;
  }
}

extern "C" void kernel_launch(void* const* d_in, const int* in_sizes, int n_in,
                              void* d_out, int out_size, void* d_ws, size_t ws_size,
                              hipStream_t stream) {
  (void)in_sizes; (void)n_in; (void)out_size; (void)ws_size;
  const float* x      = (const float*)d_in[0];
  const float* enc_w1 = (const float*)d_in[1];
  const float* enc_b1 = (const float*)d_in[2];
  const float* enc_w2 = (const float*)d_in[3];
  const float* enc_b2 = (const float*)d_in[4];
  const float* gc1_w  = (const float*)d_in[5];
  const float* gc1_b  = (const float*)d_in[6];
  const float* gc2_w  = (const float*)d_in[7];
  const float* gc2_b  = (const float*)d_in[8];
  const float* gc3_w  = (const float*)d_in[9];
  const float* gc3_b  = (const float*)d_in[10];
  const float* cls_w1 = (const float*)d_in[11];
  const float* cls_b1 = (const float*)d_in[12];
  const float* cls_w2 = (const float*)d_in[13];
  const float* cls_b2 = (const float*)d_in[14];

  float* pooled = (float*)d_ws;
  hipMemsetAsync(pooled, 0, NB * HID * sizeof(float), stream);

  fused_kernel<<<dim3(SEQ / TILE, NB), 256, 0, stream>>>(
      x, enc_w1, enc_b1, enc_w2, enc_b2,
      gc1_w, gc1_b, gc2_w, gc2_b, gc3_w, gc3_b, pooled);
  cls_kernel<<<dim3(NB), 64, 0, stream>>>(pooled, cls_w1, cls_b1, cls_w2, cls_b2,
                                          (float*)d_out);
}

// Round 4
// 241.212 us; speedup vs baseline: 5.0329x; 5.0329x over previous
//
#include <hip/hip_runtime.h>

#define SEQ  2048
#define HID  128
#define NB   32
#define TILE 32            // owned output rows per block
#define ROWS 40            // staged rows: m=0..39 <-> s = s0-3 .. s0+36
#define HSTR 132           // hbuf row stride (floats)
#define WSTR 132           // wbuf row stride (floats)

// ---------------------------------------------------------------------------
// Fully fused enc1 -> enc2 -> gc1 -> gc2 -> gc3 -> pool.
// One block per (32-row seq tile, batch); 256 threads; per-thread tile
// 5 rows x 4 cols (ty = tid>>5 owns rows ty*5..ty*5+4, tx4 = (tid&31)*4).
// Anti-spill design (R3 post-mortem): acc is 5x4=20 VGPRs, no register
// arrays live across barriers, t reuses acc in-place, no launch_bounds cap.
// W k-slices: single 16.9 KB LDS buffer, 2 barriers per slice.
// LDS = 21120 (hbuf) + 16896 (wbuf) = 38016 B -> 4 blocks/CU.
// Validity: h_enc correct for all staged in-sequence rows; out-of-sequence
// rows are zeroed at each gc epilogue (reference zero-padding); pad-row
// garbage (m=38,39 tails) never reaches the owned rows [3,34].
// ---------------------------------------------------------------------------
__global__ __launch_bounds__(256) void fused_kernel(
    const float* __restrict__ x,
    const float* __restrict__ enc_w1, const float* __restrict__ enc_b1,
    const float* __restrict__ enc_w2, const float* __restrict__ enc_b2,
    const float* __restrict__ gc1_w, const float* __restrict__ gc1_b,
    const float* __restrict__ gc2_w, const float* __restrict__ gc2_b,
    const float* __restrict__ gc3_w, const float* __restrict__ gc3_b,
    float* __restrict__ pooled)
{
  __shared__ __align__(16) float hbuf[ROWS * HSTR];   // 21120 B activations
  __shared__ __align__(16) float wbuf[32 * WSTR];     // 16896 B W slice / misc

  const int tid = threadIdx.x;
  const int tx4 = (tid & 31) * 4;
  const int ty  = tid >> 5;          // 0..7
  const int r0  = ty * 5;
  const int s0  = blockIdx.x * TILE;
  const int b   = blockIdx.y;

  // ---------------- enc1: h1 = relu(x @ w1 + b1) -> hbuf ----------------
  {
    float* xs  = wbuf;               // [ROWS][6] = 240 floats
    float* w1s = wbuf + 256;         // [6][128]  = 768 floats
    for (int f = tid; f < ROWS * 6; f += 256) {
      const int m = f / 6, c = f - m * 6;
      const int s = s0 - 3 + m;
      xs[f] = (s >= 0 && s < SEQ) ? x[((long long)b * SEQ + s) * 6 + c] : 0.f;
    }
    for (int f = tid; f < 6 * HID; f += 256) w1s[f] = enc_w1[f];
    const float4 bb = *(const float4*)&enc_b1[tx4];
    __syncthreads();

    float acc[5][4];
    #pragma unroll
    for (int i = 0; i < 5; ++i)
      acc[i][0] = acc[i][1] = acc[i][2] = acc[i][3] = 0.f;
    #pragma unroll
    for (int k = 0; k < 6; ++k) {
      const float4 w = *(const float4*)&w1s[k * HID + tx4];
      #pragma unroll
      for (int i = 0; i < 5; ++i) {
        const float a = xs[(r0 + i) * 6 + k];
        acc[i][0] = fmaf(a, w.x, acc[i][0]);
        acc[i][1] = fmaf(a, w.y, acc[i][1]);
        acc[i][2] = fmaf(a, w.z, acc[i][2]);
        acc[i][3] = fmaf(a, w.w, acc[i][3]);
      }
    }
    #pragma unroll
    for (int i = 0; i < 5; ++i) {
      float4 o;
      o.x = fmaxf(acc[i][0] + bb.x, 0.f);
      o.y = fmaxf(acc[i][1] + bb.y, 0.f);
      o.z = fmaxf(acc[i][2] + bb.z, 0.f);
      o.w = fmaxf(acc[i][3] + bb.w, 0.f);
      *(float4*)&hbuf[(r0 + i) * HSTR + tx4] = o;
    }
    // hbuf publish + wbuf release: first barrier of layer loop below
  }

  // ---------------- 4 x (128-K GEMM [+ tridiag agg + relu]) ----------------
  for (int L = 0; L < 4; ++L) {
    const float* __restrict__ Wg = (L == 0) ? enc_w2 : (L == 1) ? gc1_w
                                 : (L == 2) ? gc2_w  : gc3_w;
    const float* __restrict__ bg = (L == 0) ? enc_b2 : (L == 1) ? gc1_b
                                 : (L == 2) ? gc2_b  : gc3_b;
    // bias via global load; latency hidden behind the whole K loop
    const float4 bb = *(const float4*)&bg[tx4];

    float acc[5][4];
    #pragma unroll
    for (int i = 0; i < 5; ++i)
      acc[i][0] = acc[i][1] = acc[i][2] = acc[i][3] = 0.f;

    for (int kb = 0; kb < 4; ++kb) {
      __syncthreads();                 // wbuf readers done (prev slice/epilogue)
      #pragma unroll
      for (int q = 0; q < 4; ++q) {    // stage 32x128 W slice, 16B coalesced
        const int f = q * 256 + tid;
        const int row = f >> 5, c4 = (f & 31) << 2;
        *(float4*)&wbuf[row * WSTR + c4] =
            *(const float4*)&Wg[(kb * 32 + row) * HID + c4];
      }
      __syncthreads();                 // publish slice
      const int kbase = kb * 32;
      #pragma unroll
      for (int k4 = 0; k4 < 8; ++k4) {
        const float4 w0 = *(const float4*)&wbuf[(k4 * 4 + 0) * WSTR + tx4];
        const float4 w1 = *(const float4*)&wbuf[(k4 * 4 + 1) * WSTR + tx4];
        const float4 w2 = *(const float4*)&wbuf[(k4 * 4 + 2) * WSTR + tx4];
        const float4 w3 = *(const float4*)&wbuf[(k4 * 4 + 3) * WSTR + tx4];
        #pragma unroll
        for (int i = 0; i < 5; ++i) {
          const float4 a = *(const float4*)&hbuf[(r0 + i) * HSTR + kbase + k4 * 4];
          acc[i][0] = fmaf(a.x, w0.x, acc[i][0]);
          acc[i][1] = fmaf(a.x, w0.y, acc[i][1]);
          acc[i][2] = fmaf(a.x, w0.z, acc[i][2]);
          acc[i][3] = fmaf(a.x, w0.w, acc[i][3]);
          acc[i][0] = fmaf(a.y, w1.x, acc[i][0]);
          acc[i][1] = fmaf(a.y, w1.y, acc[i][1]);
          acc[i][2] = fmaf(a.y, w1.z, acc[i][2]);
          acc[i][3] = fmaf(a.y, w1.w, acc[i][3]);
          acc[i][0] = fmaf(a.z, w2.x, acc[i][0]);
          acc[i][1] = fmaf(a.z, w2.y, acc[i][1]);
          acc[i][2] = fmaf(a.z, w2.z, acc[i][2]);
          acc[i][3] = fmaf(a.z, w2.w, acc[i][3]);
          acc[i][0] = fmaf(a.w, w3.x, acc[i][0]);
          acc[i][1] = fmaf(a.w, w3.y, acc[i][1]);
          acc[i][2] = fmaf(a.w, w3.z, acc[i][2]);
          acc[i][3] = fmaf(a.w, w3.w, acc[i][3]);
        }
      }
    }
    __syncthreads();   // (E0) all hbuf A-reads + wbuf reads complete

    if (L == 0) {
      // enc2 epilogue: h = acc + b2 (no relu) -> hbuf
      #pragma unroll
      for (int i = 0; i < 5; ++i) {
        float4 o;
        o.x = acc[i][0] + bb.x;  o.y = acc[i][1] + bb.y;
        o.z = acc[i][2] + bb.z;  o.w = acc[i][3] + bb.w;
        *(float4*)&hbuf[(r0 + i) * HSTR + tx4] = o;
      }
      // published by next layer's first barrier
    } else {
      // t = in-sequence ? acc + b : 0   (in-place in acc)
      #pragma unroll
      for (int i = 0; i < 5; ++i) {
        const int s = s0 - 3 + r0 + i;
        const bool v = (s >= 0 && s < SEQ);
        acc[i][0] = v ? acc[i][0] + bb.x : 0.f;
        acc[i][1] = v ? acc[i][1] + bb.y : 0.f;
        acc[i][2] = v ? acc[i][2] + bb.z : 0.f;
        acc[i][3] = v ? acc[i][3] + bb.w : 0.f;
      }
      // strip-boundary exchange: xb = wbuf[0..2047]
      float* xb = wbuf;
      *(float4*)&xb[(ty * 2 + 0) * HID + tx4] = make_float4(acc[0][0], acc[0][1], acc[0][2], acc[0][3]);
      *(float4*)&xb[(ty * 2 + 1) * HID + tx4] = make_float4(acc[4][0], acc[4][1], acc[4][2], acc[4][3]);
      __syncthreads();   // (E1) publish exchange
      float4 tl = make_float4(0.f, 0.f, 0.f, 0.f), tr = tl;
      if (ty > 0) tl = *(const float4*)&xb[((ty - 1) * 2 + 1) * HID + tx4];
      if (ty < 7) tr = *(const float4*)&xb[((ty + 1) * 2 + 0) * HID + tx4];

      float4 pacc = make_float4(0.f, 0.f, 0.f, 0.f);
      #pragma unroll
      for (int i = 0; i < 5; ++i) {
        const int r = r0 + i;
        const int s = s0 - 3 + r;
        const float lfx = (i == 0) ? tl.x : acc[i - 1][0];
        const float lfy = (i == 0) ? tl.y : acc[i - 1][1];
        const float lfz = (i == 0) ? tl.z : acc[i - 1][2];
        const float lfw = (i == 0) ? tl.w : acc[i - 1][3];
        const float rtx = (i == 4) ? tr.x : acc[i + 1][0];
        const float rty = (i == 4) ? tr.y : acc[i + 1][1];
        const float rtz = (i == 4) ? tr.z : acc[i + 1][2];
        const float rtw = (i == 4) ? tr.w : acc[i + 1][3];
        const float invd = (s == 0 || s == SEQ - 1) ? (1.0f / (2.0f + 1e-8f))
                                                    : (1.0f / (3.0f + 1e-8f));
        float4 h;
        h.x = fmaxf((lfx + acc[i][0] + rtx) * invd, 0.f);
        h.y = fmaxf((lfy + acc[i][1] + rty) * invd, 0.f);
        h.z = fmaxf((lfz + acc[i][2] + rtz) * invd, 0.f);
        h.w = fmaxf((lfw + acc[i][3] + rtw) * invd, 0.f);
        if (L < 3) {
          *(float4*)&hbuf[r * HSTR + tx4] = h;   // published by next layer's barrier
        } else if (r >= 3 && r <= 34) {          // pool owned rows only
          pacc.x += h.x; pacc.y += h.y; pacc.z += h.z; pacc.w += h.w;
        }
      }
      if (L == 3) {
        float* psum = wbuf + 2048;               // disjoint from xb
        *(float4*)&psum[ty * HID + tx4] = pacc;
        __syncthreads();
        if (tid < HID) {
          float v = 0.f;
          #pragma unroll
          for (int g = 0; g < 8; ++g) v += psum[g * HID + tid];
          atomicAdd(&pooled[b * HID + tid], v);
        }
      }
    }
  }
}

// ---------------------------------------------------------------------------
// Classifier: out = relu(mean @ w1 + b1) @ w2 + b2, one block per batch row
// ---------------------------------------------------------------------------
__global__ __launch_bounds__(64) void cls_kernel(
    const float* __restrict__ pooled,
    const float* __restrict__ w1, const float* __restrict__ b1,
    const float* __restrict__ w2, const float* __restrict__ b2,
    float* __restrict__ out)
{
  __shared__ float ms[128];
  __shared__ float hid[64];
  const int b = blockIdx.x, tid = threadIdx.x;
  ms[tid] = pooled[b * 128 + tid] * (1.0f / 2048.0f);
  ms[tid + 64] = pooled[b * 128 + 64 + tid] * (1.0f / 2048.0f);
  __syncthreads();
  float a = b1[tid];
  for (int k = 0; k < 128; ++k) a = fmaf(ms[k], w1[k * 64 + tid], a);
  hid[tid] = a > 0.f ? a : 0.f;
  __syncthreads();
  if (tid < 3) {
    float o = b2[tid];
    for (int k = 0; k < 64; ++k) o = fmaf(hid[k], w2[k * 3 + tid], o);
    out[b * 3 + tid] = o;
  }
}

extern "C" void kernel_launch(void* const* d_in, const int* in_sizes, int n_in,
                              void* d_out, int out_size, void* d_ws, size_t ws_size,
                              hipStream_t stream) {
  (void)in_sizes; (void)n_in; (void)out_size; (void)ws_size;
  const float* x      = (const float*)d_in[0];
  const float* enc_w1 = (const float*)d_in[1];
  const float* enc_b1 = (const float*)d_in[2];
  const float* enc_w2 = (const float*)d_in[3];
  const float* enc_b2 = (const float*)d_in[4];
  const float* gc1_w  = (const float*)d_in[5];
  const float* gc1_b  = (const float*)d_in[6];
  const float* gc2_w  = (const float*)d_in[7];
  const float* gc2_b  = (const float*)d_in[8];
  const float* gc3_w  = (const float*)d_in[9];
  const float* gc3_b  = (const float*)d_in[10];
  const float* cls_w1 = (const float*)d_in[11];
  const float* cls_b1 = (const float*)d_in[12];
  const float* cls_w2 = (const float*)d_in[13];
  const float* cls_b2 = (const float*)d_in[14];

  float* pooled = (float*)d_ws;
  hipMemsetAsync(pooled, 0, NB * HID * sizeof(float), stream);

  fused_kernel<<<dim3(SEQ / TILE, NB), 256, 0, stream>>>(
      x, enc_w1, enc_b1, enc_w2, enc_b2,
      gc1_w, gc1_b, gc2_w, gc2_b, gc3_w, gc3_b, pooled);
  cls_kernel<<<dim3(NB), 64, 0, stream>>>(pooled, cls_w1, cls_b1, cls_w2, cls_b2,
                                          (float*)d_out);
}